// Round 3
// baseline (3598.899 us; speedup 1.0000x reference)
//
#include <hip/hip_runtime.h>

#define LL 8
#define DD 1024
#define VV 32000
#define SS 2048
#define BB 2
#define NROWS 4096          // B*S
#define DT_STEP 0.055f      // 0.5*(dt_min+dt_max)
#define HALF_DT 0.0275f
#define TUNNEL_SCALE 1.55f  // 1 + dt/dt_max

typedef __attribute__((ext_vector_type(8))) short bf16x8;
typedef __attribute__((ext_vector_type(4))) float f32x4;

static __device__ __forceinline__ float bf2f(unsigned short u){
  union { unsigned int i; float f; } v; v.i = ((unsigned int)u) << 16; return v.f;
}
static __device__ __forceinline__ unsigned short f2bf(float f){
  union { float f; unsigned int i; } v; v.f = f;
  unsigned int r = v.i + 0x7fffu + ((v.i >> 16) & 1u);
  return (unsigned short)(r >> 16);
}

// async global->LDS, 16B per lane. lds dest must be wave-uniform base; HW adds lane*16.
static __device__ __forceinline__ void gl16(const unsigned short* g, unsigned short* l){
  __builtin_amdgcn_global_load_lds(
      (const __attribute__((address_space(1))) unsigned int*)g,
      (__attribute__((address_space(3))) unsigned int*)l, 16, 0, 0);
}

__device__ __forceinline__ float block_sum256(float v, volatile float* scratch){
  #pragma unroll
  for (int off = 32; off; off >>= 1) v += __shfl_down(v, off, 64);
  int w = threadIdx.x >> 6, lane = threadIdx.x & 63;
  __syncthreads();
  if (lane == 0) scratch[w] = v;
  __syncthreads();
  return scratch[0] + scratch[1] + scratch[2] + scratch[3];
}

// ---------------- encode: phase embedding -> f32 master + bf16 hi/lo ----------------
__global__ void encode_kernel(const int* __restrict__ ids, float* __restrict__ s_f32,
                              unsigned short* __restrict__ hi, unsigned short* __restrict__ lo){
  int row = blockIdx.x;            // 0..4095 = b*S+s
  int t = threadIdx.x;
  float theta = 6.28318530717958647692f * (float)ids[row] / 32000.0f;
  #pragma unroll
  for (int i = 0; i < 2; ++i){
    int kk = t + i * 256;          // 0..511
    float ang = theta * (float)(kk + 1);
    float sv, cv; sincosf(ang, &sv, &cv);
    float c = cv * 0.03125f, s = sv * 0.03125f;   // 1/sqrt(D)
    long b0 = (long)row * DD + kk, b1 = b0 + 512;
    s_f32[b0] = c; s_f32[b1] = s;
    unsigned short ch = f2bf(c); hi[b0] = ch; lo[b0] = f2bf(c - bf2f(ch));
    unsigned short sh = f2bf(s); hi[b1] = sh; lo[b1] = f2bf(s - bf2f(sh));
  }
}

// ---------------- bf16 tiled transpose (hi+lo pair): [b][R][C] -> [b][C][R] ----------
__global__ void transpose_bf16_pair_kernel(const unsigned short* __restrict__ in_hi,
                                           const unsigned short* __restrict__ in_lo,
                                           unsigned short* __restrict__ out_hi,
                                           unsigned short* __restrict__ out_lo,
                                           int R, int C){
  __shared__ __align__(16) unsigned short tile[64][80];
  int zz = blockIdx.z;                       // (batch<<1) | sel
  const unsigned short* in = (zz & 1) ? in_lo : in_hi;
  unsigned short* out = (zz & 1) ? out_lo : out_hi;
  long ib = (long)(zz >> 1) * R * C;
  int c0 = blockIdx.x * 64, r0 = blockIdx.y * 64;
  int t = threadIdx.x;
  #pragma unroll
  for (int i = 0; i < 2; ++i){
    int j = t + i * 256; int row = j >> 3, cc = j & 7;
    *(uint4*)&tile[row][cc * 8] = *(const uint4*)(in + ib + (long)(r0 + row) * C + c0 + cc * 8);
  }
  __syncthreads();
  #pragma unroll
  for (int i = 0; i < 2; ++i){
    int j = t + i * 256; int orow = j >> 3, cc = j & 7;
    union { unsigned short u[8]; uint4 v; } tmp;
    #pragma unroll
    for (int e = 0; e < 8; ++e) tmp.u[e] = tile[cc * 8 + e][orow];
    *(uint4*)(out + ib + (long)(c0 + orow) * R + r0 + cc * 8) = tmp.v;
  }
}

// -------- f32 -> bf16 (optionally hi/lo split) transposing convert --------------------
template<bool SPLIT>
__global__ void transpose_f32_bf16_kernel(const float* __restrict__ in,
                                          unsigned short* __restrict__ ohi,
                                          unsigned short* __restrict__ olo, int R, int C){
  __shared__ float tile[64][68];
  long ib = (long)blockIdx.z * R * C;
  int c0 = blockIdx.x * 64, r0 = blockIdx.y * 64;
  int t = threadIdx.x;
  #pragma unroll
  for (int i = 0; i < 4; ++i){
    int j = t + i * 256; int row = j >> 4, cc = j & 15;
    *(float4*)&tile[row][cc * 4] = *(const float4*)(in + ib + (long)(r0 + row) * C + c0 + cc * 4);
  }
  __syncthreads();
  #pragma unroll
  for (int i = 0; i < 2; ++i){
    int j = t + i * 256; int orow = j >> 3, cc = j & 7;
    union { unsigned short u[8]; uint4 v; } th, tl;
    #pragma unroll
    for (int e = 0; e < 8; ++e){
      float v = tile[cc * 8 + e][orow];
      unsigned short h = f2bf(v); th.u[e] = h;
      if (SPLIT) tl.u[e] = f2bf(v - bf2f(h));
    }
    long ob = ib + (long)(c0 + orow) * R + r0 + cc * 8;
    *(uint4*)(ohi + ob) = th.v;
    if (SPLIT) *(uint4*)(olo + ob) = tl.v;
  }
}

// ---------------- the NT GEMM: C = alpha * A @ B^T ------------------------------------
// 128x128 tile, 4 waves. LDS [2 dbuf][128 rows][64] bf16 per operand (64 KB total):
//   plain  (SPLIT=0): row = K-64 slab, 8 chunks of 16B, content chunk c at slot c^(row&7)
//   split  (SPLIT=1): row = K-32 slab, chunks 0-3 = hi, 4-7 = lo, same XOR swizzle
// Both-sides swizzle: global_load_lds dest is LINEAR (wave-uniform base + lane*16);
// the per-lane GLOBAL address is pre-swizzled; ds_read applies the same XOR.
// Pipeline: double-buffer + counted s_waitcnt vmcnt(8) (next tile's loads stay in
// flight across the whole compute phase) + raw asm barriers (no vmcnt(0) drain).
// OUTMODE: 0 = f32 C (+ optional bias), 2 = bf16 hi/lo pair (score path)
// CAUSAL: 0 none; 1 score-mode (skip upper tiles, mask diag tile); 2 pv-mode (k-limit)
template<int SPLIT, int OUTMODE, int CAUSAL>
__global__ __launch_bounds__(256)
void gemm_nt_kernel(const unsigned short* __restrict__ Ahi, const unsigned short* __restrict__ Alo,
                    const unsigned short* __restrict__ Bhi, const unsigned short* __restrict__ Blo,
                    float* __restrict__ C, unsigned short* __restrict__ Chi,
                    unsigned short* __restrict__ Clo, const float* __restrict__ bias,
                    int K, int lda, int ldb, int ldc, int MT, int NT,
                    long batchA, long batchB, long batchC, float alpha)
{
  const int bz = blockIdx.y;
  // bijective XCD swizzle (m204) + m-fastest supertiling (bands of 8 m-tiles)
  const int nwg = MT * NT;
  const int q = nwg >> 3, r = nwg & 7;
  const int xcd = blockIdx.x & 7, off = blockIdx.x >> 3;
  const int wg = (xcd < r ? xcd * (q + 1) : r * (q + 1) + (xcd - r) * q) + off;
  const int band = wg / (NT << 3), rem = wg - band * (NT << 3);
  const int mt = (band << 3) + (rem & 7), nt = rem >> 3;
  if (CAUSAL == 1 && nt > mt) return;
  const int m0 = mt << 7, n0 = nt << 7;
  int Keff = K;
  if (CAUSAL == 2){ int kl = (mt + 1) << 7; Keff = kl < K ? kl : K; }

  __shared__ __align__(16) unsigned short sA[2][128][64];
  __shared__ __align__(16) unsigned short sB[2][128][64];

  const int tid = threadIdx.x;
  const int lane = tid & 63;
  const int w = tid >> 6;
  const int wr = w >> 1, wc = w & 1;
  const int fr = lane & 15, fc = lane >> 4;
  const int fr7 = fr & 7;

  f32x4 acc[4][4];
  #pragma unroll
  for (int i = 0; i < 4; ++i)
    #pragma unroll
    for (int j = 0; j < 4; ++j) acc[i][j] = (f32x4){0.f, 0.f, 0.f, 0.f};

  // ---- staging geometry: thread covers (row = i*32 + (tid>>3), slot = tid&7) ----
  const int srow = tid >> 3;            // 0..31
  const int slot = tid & 7;
  const int cont = slot ^ (srow & 7);   // content chunk stored at this slot
  const long aoff = (long)bz * batchA, boff = (long)bz * batchB;
  const int gcol = SPLIT ? ((cont & 3) << 3) : (cont << 3);
  const unsigned short* gA =
      (SPLIT && cont >= 4 ? Alo : Ahi) + aoff + (long)(m0 + srow) * lda + gcol;
  const unsigned short* gB =
      (SPLIT && cont >= 4 ? Blo : Bhi) + boff + (long)(n0 + srow) * ldb + gcol;
  const long rstepA = 32L * lda, rstepB = 32L * ldb;
  const int wofs = (tid & 192) << 3;    // wave-uniform chunk base (w * 1KB in elems)

  #define STAGE(buf, kt) do {                                        \
    const unsigned short* ga_ = gA + (kt);                           \
    const unsigned short* gb_ = gB + (kt);                           \
    unsigned short* la_ = &sA[buf][0][0] + wofs;                     \
    unsigned short* lb_ = &sB[buf][0][0] + wofs;                     \
    _Pragma("unroll")                                                \
    for (int i_ = 0; i_ < 4; ++i_){                                  \
      gl16(ga_ + i_ * rstepA, la_ + i_ * 2048);                      \
      gl16(gb_ + i_ * rstepB, lb_ + i_ * 2048);                      \
    }                                                                \
  } while(0)

  const int rowA = (wr * 64 + fr) * 128;   // byte offsets into [128][64] (128B rows)
  const int rowB = (wc * 64 + fr) * 128;

  #define COMPUTE(buf) do {                                                         \
    const char* bA_ = (const char*)&sA[buf][0][0];                                  \
    const char* bB_ = (const char*)&sB[buf][0][0];                                  \
    if (SPLIT){                                                                     \
      bf16x8 a0_[4], a1_[4];                                                        \
      _Pragma("unroll")                                                             \
      for (int mi = 0; mi < 4; ++mi){                                               \
        a0_[mi] = *(const bf16x8*)(bA_ + rowA + mi * 2048 + ((fc ^ fr7) << 4));     \
        a1_[mi] = *(const bf16x8*)(bA_ + rowA + mi * 2048 + (((4 + fc) ^ fr7) << 4));\
      }                                                                             \
      _Pragma("unroll")                                                             \
      for (int ni = 0; ni < 4; ++ni){                                               \
        bf16x8 b0_ = *(const bf16x8*)(bB_ + rowB + ni * 2048 + ((fc ^ fr7) << 4));  \
        bf16x8 b1_ = *(const bf16x8*)(bB_ + rowB + ni * 2048 + (((4 + fc) ^ fr7) << 4));\
        _Pragma("unroll")                                                           \
        for (int mi = 0; mi < 4; ++mi){                                             \
          acc[mi][ni] = __builtin_amdgcn_mfma_f32_16x16x32_bf16(a0_[mi], b0_, acc[mi][ni], 0, 0, 0);\
          acc[mi][ni] = __builtin_amdgcn_mfma_f32_16x16x32_bf16(a0_[mi], b1_, acc[mi][ni], 0, 0, 0);\
          acc[mi][ni] = __builtin_amdgcn_mfma_f32_16x16x32_bf16(a1_[mi], b0_, acc[mi][ni], 0, 0, 0);\
        }                                                                           \
      }                                                                             \
    } else {                                                                        \
      _Pragma("unroll")                                                             \
      for (int ks = 0; ks < 2; ++ks){                                               \
        bf16x8 a_[4];                                                               \
        _Pragma("unroll")                                                           \
        for (int mi = 0; mi < 4; ++mi)                                              \
          a_[mi] = *(const bf16x8*)(bA_ + rowA + mi * 2048 + ((((ks << 2) + fc) ^ fr7) << 4));\
        _Pragma("unroll")                                                           \
        for (int ni = 0; ni < 4; ++ni){                                             \
          bf16x8 b_ = *(const bf16x8*)(bB_ + rowB + ni * 2048 + ((((ks << 2) + fc) ^ fr7) << 4));\
          _Pragma("unroll")                                                         \
          for (int mi = 0; mi < 4; ++mi)                                            \
            acc[mi][ni] = __builtin_amdgcn_mfma_f32_16x16x32_bf16(a_[mi], b_, acc[mi][ni], 0, 0, 0);\
        }                                                                           \
      }                                                                             \
    }                                                                               \
  } while(0)

  const int step = SPLIT ? 32 : 64;
  const int ntiles = Keff / step;

  STAGE(0, 0);                               // prologue prefetch
  int cur = 0;
  for (int t = 0; t < ntiles - 1; ++t){
    asm volatile("s_barrier" ::: "memory");  // all waves done computing buf[cur^1]
    STAGE(cur ^ 1, (t + 1) * step);          // issue next tile (8 loads, stays in flight)
    asm volatile("s_waitcnt vmcnt(8)" ::: "memory");  // my tile-t loads complete
    asm volatile("s_barrier" ::: "memory");  // everyone's tile-t loads complete
    COMPUTE(cur);
    cur ^= 1;
  }
  asm volatile("s_waitcnt vmcnt(0)" ::: "memory");
  asm volatile("s_barrier" ::: "memory");
  COMPUTE(cur);

  #undef STAGE
  #undef COMPUTE

  const long coff = (long)bz * batchC;
  const int rb0 = m0 + wr * 64 + fc * 4;   // + mi*16 + r   (C: row=(lane>>4)*4+reg)
  const int cb0 = n0 + wc * 64 + fr;       // + ni*16       (C: col=lane&15)
  #pragma unroll
  for (int mi = 0; mi < 4; ++mi){
    #pragma unroll
    for (int ni = 0; ni < 4; ++ni){
      #pragma unroll
      for (int rg = 0; rg < 4; ++rg){
        int row = rb0 + mi * 16 + rg;
        int col = cb0 + ni * 16;
        float v = acc[mi][ni][rg] * alpha;
        long idx = coff + (long)row * ldc + col;
        if (OUTMODE == 0){
          if (bias) v += bias[col];
          C[idx] = v;
        } else {
          if (CAUSAL == 1 && col > row) v = 0.0f;   // causal mask (k > q)
          unsigned short h = f2bf(v);
          Chi[idx] = h;
          Clo[idx] = f2bf(v - bf2f(h));
        }
      }
    }
  }
}

// ---------------- elementwise / reduction kernels ------------------------------------
__global__ void mid_kernel(const float* __restrict__ s, const float* __restrict__ k1,
                           unsigned short* __restrict__ hi, unsigned short* __restrict__ lo){
  long i = ((long)blockIdx.x * 256 + threadIdx.x) * 4;
  float4 sv = *(const float4*)(s + i), kv = *(const float4*)(k1 + i);
  float v0 = sv.x + DT_STEP * kv.x, v1 = sv.y + DT_STEP * kv.y;
  float v2 = sv.z + DT_STEP * kv.z, v3 = sv.w + DT_STEP * kv.w;
  ushort4 hv, lv;
  hv.x = f2bf(v0); lv.x = f2bf(v0 - bf2f(hv.x));
  hv.y = f2bf(v1); lv.y = f2bf(v1 - bf2f(hv.y));
  hv.z = f2bf(v2); lv.z = f2bf(v2 - bf2f(hv.z));
  hv.w = f2bf(v3); lv.w = f2bf(v3 - bf2f(hv.w));
  *(ushort4*)(hi + i) = hv; *(ushort4*)(lo + i) = lv;
}

__global__ void ev_energy_kernel(const float* __restrict__ s, const float* __restrict__ k1,
                                 float* __restrict__ k2, float* __restrict__ energy){
  int row = blockIdx.x, t = threadIdx.x;
  long base = (long)row * DD + t * 4;
  float4 sv = *(const float4*)(s + base);
  float4 av = *(const float4*)(k1 + base);
  float4 bv = *(const float4*)(k2 + base);
  float4 ev;
  ev.x = sv.x + HALF_DT * (av.x + bv.x);
  ev.y = sv.y + HALF_DT * (av.y + bv.y);
  ev.z = sv.z + HALF_DT * (av.z + bv.z);
  ev.w = sv.w + HALF_DT * (av.w + bv.w);
  *(float4*)(k2 + base) = ev;   // ev stored in-place over k2
  __shared__ float scratch[4];
  float n2 = block_sum256(ev.x*ev.x + ev.y*ev.y + ev.z*ev.z + ev.w*ev.w, scratch);
  if (t == 0) energy[row] = sqrtf(n2);
}

__global__ void mean_energy_kernel(const float* __restrict__ energy, float* __restrict__ thr){
  int b = blockIdx.x, t = threadIdx.x;
  float s = 0.f;
  for (int j = t; j < SS; j += 256) s += energy[b * SS + j];
  __shared__ float scratch[4];
  float tot = block_sum256(s, scratch);
  if (t == 0) thr[b] = tot * (1.0f / SS);
}

__global__ void tunnel_kernel(const float* __restrict__ ev, const float* __restrict__ energy,
                              const float* __restrict__ thr,
                              unsigned short* __restrict__ hi, unsigned short* __restrict__ lo){
  int row = blockIdx.x, t = threadIdx.x;
  float scale = (energy[row] < thr[row >> 11]) ? TUNNEL_SCALE : 1.0f;
  long base = (long)row * DD + t * 4;
  float4 v = *(const float4*)(ev + base);
  v.x *= scale; v.y *= scale; v.z *= scale; v.w *= scale;
  ushort4 hv, lv;
  hv.x = f2bf(v.x); lv.x = f2bf(v.x - bf2f(hv.x));
  hv.y = f2bf(v.y); lv.y = f2bf(v.y - bf2f(hv.y));
  hv.z = f2bf(v.z); lv.z = f2bf(v.z - bf2f(hv.z));
  hv.w = f2bf(v.w); lv.w = f2bf(v.w - bf2f(hv.w));
  *(ushort4*)(hi + base) = hv; *(ushort4*)(lo + base) = lv;
}

__global__ void ln_kernel(const float* __restrict__ h, const float* __restrict__ w,
                          const float* __restrict__ b, float* __restrict__ s_f32,
                          unsigned short* __restrict__ hi, unsigned short* __restrict__ lo){
  int row = blockIdx.x, t = threadIdx.x;
  long base = (long)row * DD + t * 4;
  float4 xv = *(const float4*)(h + base);
  __shared__ float scratch[4];
  float sum = block_sum256(xv.x + xv.y + xv.z + xv.w, scratch);
  float ssq = block_sum256(xv.x*xv.x + xv.y*xv.y + xv.z*xv.z + xv.w*xv.w, scratch);
  float mu = sum * (1.0f / DD);
  float var = ssq * (1.0f / DD) - mu * mu;
  float rstd = rsqrtf(var + 1e-5f);
  float4 wv = *(const float4*)(w + t * 4), bv = *(const float4*)(b + t * 4);
  float y0 = (xv.x - mu) * rstd * wv.x + bv.x;
  float y1 = (xv.y - mu) * rstd * wv.y + bv.y;
  float y2 = (xv.z - mu) * rstd * wv.z + bv.z;
  float y3 = (xv.w - mu) * rstd * wv.w + bv.w;
  float4 o; o.x = y0; o.y = y1; o.z = y2; o.w = y3;
  *(float4*)(s_f32 + base) = o;
  ushort4 hv, lv;
  hv.x = f2bf(y0); lv.x = f2bf(y0 - bf2f(hv.x));
  hv.y = f2bf(y1); lv.y = f2bf(y1 - bf2f(hv.y));
  hv.z = f2bf(y2); lv.z = f2bf(y2 - bf2f(hv.z));
  hv.w = f2bf(y3); lv.w = f2bf(y3 - bf2f(hv.w));
  *(ushort4*)(hi + base) = hv; *(ushort4*)(lo + base) = lv;
}

// final LN + unit-normalize -> bf16 (plain; un-amplified error)
__global__ void fln_kernel(const float* __restrict__ s, const float* __restrict__ w,
                           const float* __restrict__ b, unsigned short* __restrict__ uhi){
  int row = blockIdx.x, t = threadIdx.x;
  long base = (long)row * DD + t * 4;
  float4 xv = *(const float4*)(s + base);
  __shared__ float scratch[4];
  float sum = block_sum256(xv.x + xv.y + xv.z + xv.w, scratch);
  float ssq = block_sum256(xv.x*xv.x + xv.y*xv.y + xv.z*xv.z + xv.w*xv.w, scratch);
  float mu = sum * (1.0f / DD);
  float var = ssq * (1.0f / DD) - mu * mu;
  float rstd = rsqrtf(var + 1e-5f);
  float4 wv = *(const float4*)(w + t * 4), bv = *(const float4*)(b + t * 4);
  float y0 = (xv.x - mu) * rstd * wv.x + bv.x;
  float y1 = (xv.y - mu) * rstd * wv.y + bv.y;
  float y2 = (xv.z - mu) * rstd * wv.z + bv.z;
  float y3 = (xv.w - mu) * rstd * wv.w + bv.w;
  float n2 = block_sum256(y0*y0 + y1*y1 + y2*y2 + y3*y3, scratch);
  float inv = 1.0f / (sqrtf(n2) + 1e-12f);
  ushort4 o;
  o.x = f2bf(y0 * inv); o.y = f2bf(y1 * inv);
  o.z = f2bf(y2 * inv); o.w = f2bf(y3 * inv);
  *(ushort4*)(uhi + base) = o;
}

// ---------------- loss --------------------------------------------------------------
__global__ void loss_rows_kernel(const float* __restrict__ logits, const int* __restrict__ labels,
                                 float* __restrict__ lrow){
  int idx = blockIdx.x;               // 0..4093
  int b = idx / (SS - 1), q = idx - b * (SS - 1);
  const float* rowp = logits + (long)(b * SS + q) * VV;
  int t = threadIdx.x;
  float m = -1e30f, l = 0.f;
  for (int j = t; j < VV / 4; j += 256){
    float4 v = *(const float4*)(rowp + j * 4);
    float mv = fmaxf(fmaxf(v.x, v.y), fmaxf(v.z, v.w));
    if (mv > m){ l *= __expf(m - mv); m = mv; }
    l += __expf(v.x - m) + __expf(v.y - m) + __expf(v.z - m) + __expf(v.w - m);
  }
  __shared__ float sm[256], sl[256];
  sm[t] = m; sl[t] = l;
  __syncthreads();
  for (int off = 128; off; off >>= 1){
    if (t < off){
      float m2 = sm[t + off], l2 = sl[t + off];
      float M = fmaxf(sm[t], m2);
      sl[t] = sl[t] * __expf(sm[t] - M) + l2 * __expf(m2 - M);
      sm[t] = M;
    }
    __syncthreads();
  }
  if (t == 0){
    float lse = sm[0] + __logf(sl[0]);
    float tl = rowp[labels[b * SS + q + 1]];
    lrow[idx] = lse - tl;
  }
}

__global__ void loss_reduce_kernel(const float* __restrict__ lrow, float* __restrict__ dst){
  __shared__ float scratch[4];
  float s = 0.f;
  for (int j = threadIdx.x; j < BB * (SS - 1); j += 256) s += lrow[j];
  float tot = block_sum256(s, scratch);
  if (threadIdx.x == 0) dst[0] = tot / (float)(BB * (SS - 1));
}

// ---------------- launch ------------------------------------------------------------
extern "C" void kernel_launch(void* const* d_in, const int* in_sizes, int n_in,
                              void* d_out, int out_size, void* d_ws, size_t ws_size,
                              hipStream_t stream) {
  const int*   ids    = (const int*)d_in[0];
  const int*   labels = (const int*)d_in[1];
  const float* proj_w = (const float*)d_in[2];
  const float* proj_b = (const float*)d_in[3];
  const float* ln_w   = (const float*)d_in[4];
  const float* ln_b   = (const float*)d_in[5];
  const float* fln_w  = (const float*)d_in[6];
  const float* fln_b  = (const float*)d_in[7];
  const float* out_w  = (const float*)d_in[8];
  float* out = (float*)d_out;

  char* ws = (char*)d_ws;
  float*          s_f32 = (float*)(ws + 0);                    // 16.78 MB
  unsigned short* op_hi = (unsigned short*)(ws + 16777216);    //  8.39 MB (states/mid/ev/u hi)
  unsigned short* op_lo = (unsigned short*)(ws + 25165824);    //  8.39 MB
  unsigned short* T_hi  = (unsigned short*)(ws + 33554432);    //  8.39 MB (transposed operand)
  unsigned short* T_lo  = (unsigned short*)(ws + 41943040);    //  8.39 MB
  float*          k1    = (float*)(ws + 50331648);             // 16.78 MB (also h pre-LN)
  float*          k2    = (float*)(ws + 67108864);             // 16.78 MB (also ev)
  unsigned short* sc_hi = (unsigned short*)(ws + 83886080);    //  8.39 MB (score hi)
  unsigned short* sc_lo = (unsigned short*)(ws + 92274688);    //  8.39 MB
  unsigned short* WhiT  = (unsigned short*)(ws + 100663296);   // 16.78 MB [L][n][k]
  unsigned short* WloT  = (unsigned short*)(ws + 117440512);   // 16.78 MB
  float*          energy= (float*)(ws + 134217728);
  float*          thr   = (float*)(ws + 134234112);
  float*          lrow  = (float*)(ws + 134234368);
  unsigned short* owT   = T_hi;  // 65.54 MB, overlays T/k/score zone (dead at vocab time)

  // proj_w [L][k][n] -> WhiT/WloT [L][n][k] (fp32-split bf16)
  transpose_f32_bf16_kernel<true><<<dim3(16, 16, 8), 256, 0, stream>>>(proj_w, WhiT, WloT, DD, DD);
  // encode
  encode_kernel<<<NROWS, 256, 0, stream>>>(ids, s_f32, op_hi, op_lo);
  transpose_bf16_pair_kernel<<<dim3(16, 32, 4), 256, 0, stream>>>(op_hi, op_lo, T_hi, T_lo, SS, DD);

  for (int l = 0; l < LL; ++l){
    // score1 = tril(states @ statesT)/32  -> bf16 hi/lo
    gemm_nt_kernel<1, 2, 1><<<dim3(256, 2), 256, 0, stream>>>(
        op_hi, op_lo, op_hi, op_lo, nullptr, sc_hi, sc_lo, nullptr,
        DD, DD, DD, SS, 16, 16, (long)SS * DD, (long)SS * DD, (long)SS * SS, 0.03125f);
    // k1 = score1 @ states
    gemm_nt_kernel<1, 0, 2><<<dim3(128, 2), 256, 0, stream>>>(
        sc_hi, sc_lo, T_hi, T_lo, k1, nullptr, nullptr, nullptr,
        SS, SS, SS, DD, 16, 8, (long)SS * SS, (long)DD * SS, (long)SS * DD, 1.0f);
    // mid = states + dt*k1
    mid_kernel<<<NROWS, 256, 0, stream>>>(s_f32, k1, op_hi, op_lo);
    transpose_bf16_pair_kernel<<<dim3(16, 32, 4), 256, 0, stream>>>(op_hi, op_lo, T_hi, T_lo, SS, DD);
    // score2 = tril(mid @ midT)/32
    gemm_nt_kernel<1, 2, 1><<<dim3(256, 2), 256, 0, stream>>>(
        op_hi, op_lo, op_hi, op_lo, nullptr, sc_hi, sc_lo, nullptr,
        DD, DD, DD, SS, 16, 16, (long)SS * DD, (long)SS * DD, (long)SS * SS, 0.03125f);
    // k2 = score2 @ mid
    gemm_nt_kernel<1, 0, 2><<<dim3(128, 2), 256, 0, stream>>>(
        sc_hi, sc_lo, T_hi, T_lo, k2, nullptr, nullptr, nullptr,
        SS, SS, SS, DD, 16, 8, (long)SS * SS, (long)DD * SS, (long)SS * DD, 1.0f);
    // ev = states + 0.5*dt*(k1+k2) (in-place over k2) + row energies
    ev_energy_kernel<<<NROWS, 256, 0, stream>>>(s_f32, k1, k2, energy);
    mean_energy_kernel<<<BB, 256, 0, stream>>>(energy, thr);
    tunnel_kernel<<<NROWS, 256, 0, stream>>>(k2, energy, thr, op_hi, op_lo);
    // h = ev @ proj_w[l] + proj_b[l]  (into k1)
    gemm_nt_kernel<1, 0, 0><<<dim3(256, 1), 256, 0, stream>>>(
        op_hi, op_lo, WhiT + (long)l * DD * DD, WloT + (long)l * DD * DD,
        k1, nullptr, nullptr, proj_b + l * DD, DD, DD, DD, DD, 32, 8, 0, 0, 0, 1.0f);
    // states = LN(h)
    ln_kernel<<<NROWS, 256, 0, stream>>>(k1, ln_w + l * DD, ln_b + l * DD, s_f32, op_hi, op_lo);
    if (l < LL - 1){
      transpose_bf16_pair_kernel<<<dim3(16, 32, 4), 256, 0, stream>>>(op_hi, op_lo, T_hi, T_lo, SS, DD);
    }
  }

  // out_w [k][v] -> owT [v][k] bf16 (plain); u = unit(LN(states)) -> op_hi
  transpose_f32_bf16_kernel<false><<<dim3(500, 16, 1), 256, 0, stream>>>(out_w, owT, nullptr, DD, VV);
  fln_kernel<<<NROWS, 256, 0, stream>>>(s_f32, fln_w, fln_b, op_hi);
  // logits = u @ out_w  (plain bf16)
  gemm_nt_kernel<0, 0, 0><<<dim3(8000, 1), 256, 0, stream>>>(
      op_hi, op_hi, owT, owT, out, nullptr, nullptr, nullptr,
      DD, DD, DD, VV, 32, 250, 0, 0, 0, 1.0f);
  // loss
  loss_rows_kernel<<<BB * (SS - 1), 256, 0, stream>>>(out, labels, lrow);
  loss_reduce_kernel<<<1, 256, 0, stream>>>(lrow, out + (long)NROWS * VV);
}

// Round 4
// 3000.375 us; speedup vs baseline: 1.1995x; 1.1995x over previous
//
#include <hip/hip_runtime.h>

#define LL 8
#define DD 1024
#define VV 32000
#define SS 2048
#define BB 2
#define NROWS 4096          // B*S
#define DT_STEP 0.055f      // 0.5*(dt_min+dt_max)
#define HALF_DT 0.0275f
#define TUNNEL_SCALE 1.55f  // 1 + dt/dt_max

typedef __attribute__((ext_vector_type(8))) short bf16x8;
typedef __attribute__((ext_vector_type(4))) float f32x4;

static __device__ __forceinline__ float bf2f(unsigned short u){
  union { unsigned int i; float f; } v; v.i = ((unsigned int)u) << 16; return v.f;
}
static __device__ __forceinline__ unsigned short f2bf(float f){
  union { float f; unsigned int i; } v; v.f = f;
  unsigned int r = v.i + 0x7fffu + ((v.i >> 16) & 1u);
  return (unsigned short)(r >> 16);
}

// async global->LDS, 16B per lane. lds dest must be wave-uniform base; HW adds lane*16.
static __device__ __forceinline__ void gl16(const unsigned short* g, unsigned short* l){
  __builtin_amdgcn_global_load_lds(
      (const __attribute__((address_space(1))) unsigned int*)g,
      (__attribute__((address_space(3))) unsigned int*)l, 16, 0, 0);
}

__device__ __forceinline__ float block_sum256(float v, volatile float* scratch){
  #pragma unroll
  for (int off = 32; off; off >>= 1) v += __shfl_down(v, off, 64);
  int w = threadIdx.x >> 6, lane = threadIdx.x & 63;
  __syncthreads();
  if (lane == 0) scratch[w] = v;
  __syncthreads();
  return scratch[0] + scratch[1] + scratch[2] + scratch[3];
}

// ---------------- encode: phase embedding -> f32 master + bf16 hi/lo ----------------
__global__ void encode_kernel(const int* __restrict__ ids, float* __restrict__ s_f32,
                              unsigned short* __restrict__ hi, unsigned short* __restrict__ lo){
  int row = blockIdx.x;            // 0..4095 = b*S+s
  int t = threadIdx.x;
  float theta = 6.28318530717958647692f * (float)ids[row] / 32000.0f;
  #pragma unroll
  for (int i = 0; i < 2; ++i){
    int kk = t + i * 256;          // 0..511
    float ang = theta * (float)(kk + 1);
    float sv, cv; sincosf(ang, &sv, &cv);
    float c = cv * 0.03125f, s = sv * 0.03125f;   // 1/sqrt(D)
    long b0 = (long)row * DD + kk, b1 = b0 + 512;
    s_f32[b0] = c; s_f32[b1] = s;
    unsigned short ch = f2bf(c); hi[b0] = ch; lo[b0] = f2bf(c - bf2f(ch));
    unsigned short sh = f2bf(s); hi[b1] = sh; lo[b1] = f2bf(s - bf2f(sh));
  }
}

// ---------------- bf16 tiled transpose (hi+lo pair): [b][R][C] -> [b][C][R] ----------
__global__ void transpose_bf16_pair_kernel(const unsigned short* __restrict__ in_hi,
                                           const unsigned short* __restrict__ in_lo,
                                           unsigned short* __restrict__ out_hi,
                                           unsigned short* __restrict__ out_lo,
                                           int R, int C){
  __shared__ __align__(16) unsigned short tile[64][80];
  int zz = blockIdx.z;                       // (batch<<1) | sel
  const unsigned short* in = (zz & 1) ? in_lo : in_hi;
  unsigned short* out = (zz & 1) ? out_lo : out_hi;
  long ib = (long)(zz >> 1) * R * C;
  int c0 = blockIdx.x * 64, r0 = blockIdx.y * 64;
  int t = threadIdx.x;
  #pragma unroll
  for (int i = 0; i < 2; ++i){
    int j = t + i * 256; int row = j >> 3, cc = j & 7;
    *(uint4*)&tile[row][cc * 8] = *(const uint4*)(in + ib + (long)(r0 + row) * C + c0 + cc * 8);
  }
  __syncthreads();
  #pragma unroll
  for (int i = 0; i < 2; ++i){
    int j = t + i * 256; int orow = j >> 3, cc = j & 7;
    union { unsigned short u[8]; uint4 v; } tmp;
    #pragma unroll
    for (int e = 0; e < 8; ++e) tmp.u[e] = tile[cc * 8 + e][orow];
    *(uint4*)(out + ib + (long)(c0 + orow) * R + r0 + cc * 8) = tmp.v;
  }
}

// -------- f32 -> bf16 (optionally hi/lo split) transposing convert --------------------
template<bool SPLIT>
__global__ void transpose_f32_bf16_kernel(const float* __restrict__ in,
                                          unsigned short* __restrict__ ohi,
                                          unsigned short* __restrict__ olo, int R, int C){
  __shared__ float tile[64][68];
  long ib = (long)blockIdx.z * R * C;
  int c0 = blockIdx.x * 64, r0 = blockIdx.y * 64;
  int t = threadIdx.x;
  #pragma unroll
  for (int i = 0; i < 4; ++i){
    int j = t + i * 256; int row = j >> 4, cc = j & 15;
    *(float4*)&tile[row][cc * 4] = *(const float4*)(in + ib + (long)(r0 + row) * C + c0 + cc * 4);
  }
  __syncthreads();
  #pragma unroll
  for (int i = 0; i < 2; ++i){
    int j = t + i * 256; int orow = j >> 3, cc = j & 7;
    union { unsigned short u[8]; uint4 v; } th, tl;
    #pragma unroll
    for (int e = 0; e < 8; ++e){
      float v = tile[cc * 8 + e][orow];
      unsigned short h = f2bf(v); th.u[e] = h;
      if (SPLIT) tl.u[e] = f2bf(v - bf2f(h));
    }
    long ob = ib + (long)(c0 + orow) * R + r0 + cc * 8;
    *(uint4*)(ohi + ob) = th.v;
    if (SPLIT) *(uint4*)(olo + ob) = tl.v;
  }
}

// ---------------- split NT GEMM (128x128, 8 waves): C = alpha * A @ B^T ---------------
// Operands as (hi,lo) bf16 pairs -> 3 MFMA products (fp32-class accuracy).
// LDS [2 dbuf][128 rows][64]: row = K-32 slab, chunks 0-3 hi / 4-7 lo, slot = chunk^(row&7).
// 8 waves (512 thr), wave grid 2x4, each wave 64x32 of C -> 2-4 waves/SIMD for TLP.
// OUTMODE: 0 = f32 C (+bias); 2 = bf16 hi/lo (score); 3 = f32 C + mid=S+dt*C hi/lo;
//          4 = C = S + 0.5dt*(K1+v)  (ev, in-place logical)
// CAUSAL: 0 none; 1 score-mode (skip upper tiles, mask diag); 2 pv-mode (k-limit)
template<int OUTMODE, int CAUSAL>
__global__ __launch_bounds__(512, 4)
void gemm_nt_kernel(const unsigned short* __restrict__ Ahi, const unsigned short* __restrict__ Alo,
                    const unsigned short* __restrict__ Bhi, const unsigned short* __restrict__ Blo,
                    float* __restrict__ C, unsigned short* __restrict__ Chi,
                    unsigned short* __restrict__ Clo, const float* __restrict__ bias,
                    const float* __restrict__ Sf, const float* __restrict__ K1f,
                    int K, int lda, int ldb, int ldc, int MT, int NT,
                    long batchA, long batchB, long batchC, float alpha)
{
  const int bz = blockIdx.y;
  const int nwg = MT * NT;
  const int q = nwg >> 3, r = nwg & 7;
  const int xcd = blockIdx.x & 7, off = blockIdx.x >> 3;
  const int wg = (xcd < r ? xcd * (q + 1) : r * (q + 1) + (xcd - r) * q) + off;
  const int band = wg / (NT << 3), rem = wg - band * (NT << 3);
  const int mt = (band << 3) + (rem & 7), nt = rem >> 3;
  if (CAUSAL == 1 && nt > mt) return;
  const int m0 = mt << 7, n0 = nt << 7;
  int Keff = K;
  if (CAUSAL == 2){ int kl = (mt + 1) << 7; Keff = kl < K ? kl : K; }

  __shared__ __align__(16) unsigned short sA[2][128][64];
  __shared__ __align__(16) unsigned short sB[2][128][64];

  const int tid = threadIdx.x;
  const int lane = tid & 63;
  const int w = tid >> 6;              // 0..7
  const int wr = w >> 2, wc = w & 3;   // 2 x 4 wave grid, 64x32 per wave
  const int fr = lane & 15, fc = lane >> 4;
  const int fr7 = fr & 7;

  f32x4 acc[4][2];
  #pragma unroll
  for (int i = 0; i < 4; ++i)
    #pragma unroll
    for (int j = 0; j < 2; ++j) acc[i][j] = (f32x4){0.f, 0.f, 0.f, 0.f};

  // staging: thread = (srow = tid>>3 in 0..63, slot = tid&7); 2 issues/operand/tile
  const int srow = tid >> 3, slot = tid & 7;
  const int cont = slot ^ (srow & 7);         // content chunk at this slot
  const long aoff = (long)bz * batchA, boff = (long)bz * batchB;
  const int gcol = (cont & 3) << 3;
  const unsigned short* gA = (cont >= 4 ? Alo : Ahi) + aoff + (long)(m0 + srow) * lda + gcol;
  const unsigned short* gB = (cont >= 4 ? Blo : Bhi) + boff + (long)(n0 + srow) * ldb + gcol;
  const long rstepA = 64L * lda, rstepB = 64L * ldb;
  const int wofs = w << 9;                    // wave base: w*8 rows * 64 elems

  #define STAGE(buf, kt) do {                                        \
    gl16(gA + (kt),          &sA[buf][0][0] + wofs);                 \
    gl16(gA + (kt) + rstepA, &sA[buf][0][0] + 4096 + wofs);          \
    gl16(gB + (kt),          &sB[buf][0][0] + wofs);                 \
    gl16(gB + (kt) + rstepB, &sB[buf][0][0] + 4096 + wofs);          \
  } while(0)

  const int oh = (fc ^ fr7) << 4;
  const int ol = ((4 + fc) ^ fr7) << 4;

  #define COMPUTE(buf) do {                                                         \
    const char* bA_ = (const char*)&sA[buf][0][0];                                  \
    const char* bB_ = (const char*)&sB[buf][0][0];                                  \
    bf16x8 ah_[4], al_[4];                                                          \
    _Pragma("unroll")                                                               \
    for (int mi = 0; mi < 4; ++mi){                                                 \
      const char* p_ = bA_ + (wr * 64 + mi * 16 + fr) * 128;                        \
      ah_[mi] = *(const bf16x8*)(p_ + oh);                                          \
      al_[mi] = *(const bf16x8*)(p_ + ol);                                          \
    }                                                                               \
    _Pragma("unroll")                                                               \
    for (int ni = 0; ni < 2; ++ni){                                                 \
      const char* pb_ = bB_ + (wc * 32 + ni * 16 + fr) * 128;                       \
      bf16x8 bh_ = *(const bf16x8*)(pb_ + oh);                                      \
      bf16x8 bl_ = *(const bf16x8*)(pb_ + ol);                                      \
      _Pragma("unroll")                                                             \
      for (int mi = 0; mi < 4; ++mi){                                               \
        acc[mi][ni] = __builtin_amdgcn_mfma_f32_16x16x32_bf16(ah_[mi], bh_, acc[mi][ni], 0, 0, 0);\
        acc[mi][ni] = __builtin_amdgcn_mfma_f32_16x16x32_bf16(ah_[mi], bl_, acc[mi][ni], 0, 0, 0);\
        acc[mi][ni] = __builtin_amdgcn_mfma_f32_16x16x32_bf16(al_[mi], bh_, acc[mi][ni], 0, 0, 0);\
      }                                                                             \
    }                                                                               \
  } while(0)

  const int ntiles = Keff >> 5;

  STAGE(0, 0);
  int cur = 0;
  for (int t = 0; t < ntiles - 1; ++t){
    asm volatile("s_barrier" ::: "memory");           // prev compute on cur^1 done
    STAGE(cur ^ 1, (t + 1) << 5);                     // issue next tile (4 loads fly)
    asm volatile("s_waitcnt vmcnt(4)" ::: "memory");  // my tile-t loads landed
    asm volatile("s_barrier" ::: "memory");           // everyone's landed
    COMPUTE(cur);
    cur ^= 1;
  }
  asm volatile("s_waitcnt vmcnt(0)" ::: "memory");
  asm volatile("s_barrier" ::: "memory");
  COMPUTE(cur);

  #undef STAGE
  #undef COMPUTE

  const long coff = (long)bz * batchC;
  const int rb0 = m0 + wr * 64 + fc * 4;   // + mi*16 + rg
  const int cb0 = n0 + wc * 32 + fr;       // + ni*16
  #pragma unroll
  for (int mi = 0; mi < 4; ++mi){
    #pragma unroll
    for (int ni = 0; ni < 2; ++ni){
      #pragma unroll
      for (int rg = 0; rg < 4; ++rg){
        int row = rb0 + mi * 16 + rg;
        int col = cb0 + ni * 16;
        float v = acc[mi][ni][rg] * alpha;
        long idx = coff + (long)row * ldc + col;
        if (OUTMODE == 0){
          if (bias) v += bias[col];
          C[idx] = v;
        } else if (OUTMODE == 2){
          if (CAUSAL == 1 && col > row) v = 0.0f;   // causal mask (k > q)
          unsigned short h = f2bf(v);
          Chi[idx] = h;
          Clo[idx] = f2bf(v - bf2f(h));
        } else if (OUTMODE == 3){                   // k1 + fused mid = s + dt*k1
          C[idx] = v;
          float m = Sf[idx] + DT_STEP * v;
          unsigned short h = f2bf(m);
          Chi[idx] = h;
          Clo[idx] = f2bf(m - bf2f(h));
        } else {                                    // fused ev = s + 0.5dt*(k1+k2)
          C[idx] = Sf[idx] + HALF_DT * (K1f[idx] + v);
        }
      }
    }
  }
}

// ---------------- 256x256 8-wave multi-phase GEMM (vocab): C = A @ B^T ---------------
// BK=64, 4 phases/K-tile, counted vmcnt(2) at p0 only, raw barriers, setprio on MFMA.
// LDS 128 KB dbuf, chunk-XOR swizzle both sides (proven conflict-free r3).
__global__ __launch_bounds__(512, 2)
void gemm256_kernel(const unsigned short* __restrict__ A,    // [4096][1024] bf16
                    const unsigned short* __restrict__ Bt,   // [32000][1024] bf16
                    float* __restrict__ C)                   // [4096][32000] f32
{
  const int MT = 16, NT = 125;
  const int nwg = MT * NT;
  const int q = nwg >> 3, r = nwg & 7;
  const int xcd = blockIdx.x & 7, off = blockIdx.x >> 3;
  const int wg = (xcd < r ? xcd * (q + 1) : r * (q + 1) + (xcd - r) * q) + off;
  const int band = wg / (NT << 3), rem = wg - band * (NT << 3);
  const int mt = (band << 3) + (rem & 7), nt = rem >> 3;
  const int m0 = mt << 8, n0 = nt << 8;

  __shared__ __align__(16) unsigned short sA[2][256][64];
  __shared__ __align__(16) unsigned short sB[2][256][64];

  const int tid = threadIdx.x;
  const int lane = tid & 63;
  const int w = tid >> 6;
  const int wr = w >> 2, wc = w & 3;     // 2 x 4, each wave 128x64 of C
  const int fr = lane & 15, fc = lane >> 4;
  const int fr7 = fr & 7;

  f32x4 acc[8][4];
  #pragma unroll
  for (int i = 0; i < 8; ++i)
    #pragma unroll
    for (int j = 0; j < 4; ++j) acc[i][j] = (f32x4){0.f, 0.f, 0.f, 0.f};

  const int srow = tid >> 3, slot = tid & 7;
  const int cont = slot ^ (srow & 7);
  const unsigned short* gA = A  + (long)(m0 + srow) * DD + (cont << 3);
  const unsigned short* gB = Bt + (long)(n0 + srow) * DD + (cont << 3);
  const int wofs = w << 9;               // w*8 rows * 64 elems

  #define SGA(buf, kt, i) gl16(gA + (long)((i) * 64) * DD + (kt), &sA[buf][0][0] + (i) * 4096 + wofs)
  #define SGB(buf, kt, i) gl16(gB + (long)((i) * 64) * DD + (kt), &sB[buf][0][0] + (i) * 4096 + wofs)

  const int oh = (fc ^ fr7) << 4;        // ks=0 chunk
  const int ol = ((4 + fc) ^ fr7) << 4;  // ks=1 chunk

  // prologue: stage tile 0 fully (8 issues)
  #pragma unroll
  for (int i = 0; i < 4; ++i){ SGA(0, 0, i); SGB(0, 0, i); }

  int cur = 0;
  for (int t = 0; t < 16; ++t){
    const int nk = (t + 1) << 6;
    const bool stg = (t < 15);
    const char* bA = (const char*)&sA[cur][0][0];
    const char* bB = (const char*)&sB[cur][0][0];
    bf16x8 aq[4][2], bq[4][2];

    // ---- phase 0: stage A0,A1 of t+1; certify tile t landed; a-half0 + b0,b1; MFMA q(lo,lo)
    if (stg){ SGA(cur ^ 1, nk, 0); SGA(cur ^ 1, nk, 1);
              asm volatile("s_waitcnt vmcnt(2)" ::: "memory"); }
    else    { asm volatile("s_waitcnt vmcnt(0)" ::: "memory"); }
    asm volatile("s_barrier" ::: "memory");
    #pragma unroll
    for (int mi = 0; mi < 4; ++mi){
      const char* p = bA + (wr * 128 + mi * 16 + fr) * 128;
      aq[mi][0] = *(const bf16x8*)(p + oh);
      aq[mi][1] = *(const bf16x8*)(p + ol);
    }
    #pragma unroll
    for (int ni = 0; ni < 2; ++ni){
      const char* p = bB + (wc * 64 + ni * 16 + fr) * 128;
      bq[ni][0] = *(const bf16x8*)(p + oh);
      bq[ni][1] = *(const bf16x8*)(p + ol);
    }
    __builtin_amdgcn_s_setprio(1);
    #pragma unroll
    for (int ks = 0; ks < 2; ++ks)
      #pragma unroll
      for (int mi = 0; mi < 4; ++mi)
        #pragma unroll
        for (int ni = 0; ni < 2; ++ni)
          acc[mi][ni] = __builtin_amdgcn_mfma_f32_16x16x32_bf16(aq[mi][ks], bq[ni][ks], acc[mi][ni], 0, 0, 0);
    __builtin_amdgcn_s_setprio(0);

    // ---- phase 1: stage A2,A3; read b2,b3; MFMA q(lo,hi)
    if (stg){ SGA(cur ^ 1, nk, 2); SGA(cur ^ 1, nk, 3); }
    asm volatile("s_barrier" ::: "memory");
    #pragma unroll
    for (int ni = 2; ni < 4; ++ni){
      const char* p = bB + (wc * 64 + ni * 16 + fr) * 128;
      bq[ni][0] = *(const bf16x8*)(p + oh);
      bq[ni][1] = *(const bf16x8*)(p + ol);
    }
    __builtin_amdgcn_s_setprio(1);
    #pragma unroll
    for (int ks = 0; ks < 2; ++ks)
      #pragma unroll
      for (int mi = 0; mi < 4; ++mi)
        #pragma unroll
        for (int ni = 2; ni < 4; ++ni)
          acc[mi][ni] = __builtin_amdgcn_mfma_f32_16x16x32_bf16(aq[mi][ks], bq[ni][ks], acc[mi][ni], 0, 0, 0);
    __builtin_amdgcn_s_setprio(0);

    // ---- phase 2: stage B0,B1; read a-half1; MFMA q(hi,hi)
    if (stg){ SGB(cur ^ 1, nk, 0); SGB(cur ^ 1, nk, 1); }
    asm volatile("s_barrier" ::: "memory");
    #pragma unroll
    for (int mi = 0; mi < 4; ++mi){
      const char* p = bA + (wr * 128 + (mi + 4) * 16 + fr) * 128;
      aq[mi][0] = *(const bf16x8*)(p + oh);
      aq[mi][1] = *(const bf16x8*)(p + ol);
    }
    __builtin_amdgcn_s_setprio(1);
    #pragma unroll
    for (int ks = 0; ks < 2; ++ks)
      #pragma unroll
      for (int mi = 0; mi < 4; ++mi)
        #pragma unroll
        for (int ni = 2; ni < 4; ++ni)
          acc[mi + 4][ni] = __builtin_amdgcn_mfma_f32_16x16x32_bf16(aq[mi][ks], bq[ni][ks], acc[mi + 4][ni], 0, 0, 0);
    __builtin_amdgcn_s_setprio(0);

    // ---- phase 3: stage B2,B3; MFMA q(hi,lo)  (bq[0..1] still live)
    if (stg){ SGB(cur ^ 1, nk, 2); SGB(cur ^ 1, nk, 3); }
    asm volatile("s_barrier" ::: "memory");
    __builtin_amdgcn_s_setprio(1);
    #pragma unroll
    for (int ks = 0; ks < 2; ++ks)
      #pragma unroll
      for (int mi = 0; mi < 4; ++mi)
        #pragma unroll
        for (int ni = 0; ni < 2; ++ni)
          acc[mi + 4][ni] = __builtin_amdgcn_mfma_f32_16x16x32_bf16(aq[mi][ks], bq[ni][ks], acc[mi + 4][ni], 0, 0, 0);
    __builtin_amdgcn_s_setprio(0);

    cur ^= 1;
  }
  #undef SGA
  #undef SGB

  const int rb0 = m0 + wr * 128 + fc * 4;
  const int cb0 = n0 + wc * 64 + fr;
  #pragma unroll
  for (int mi = 0; mi < 8; ++mi){
    #pragma unroll
    for (int ni = 0; ni < 4; ++ni){
      #pragma unroll
      for (int rg = 0; rg < 4; ++rg){
        int row = rb0 + mi * 16 + rg;
        int col = cb0 + ni * 16;
        C[(long)row * VV + col] = acc[mi][ni][rg];
      }
    }
  }
}

// ---------------- elementwise / reduction kernels ------------------------------------
__global__ void energy_kernel(const float* __restrict__ ev, float* __restrict__ energy){
  int row = blockIdx.x, t = threadIdx.x;
  long base = (long)row * DD + t * 4;
  float4 v = *(const float4*)(ev + base);
  __shared__ float scratch[4];
  float n2 = block_sum256(v.x*v.x + v.y*v.y + v.z*v.z + v.w*v.w, scratch);
  if (t == 0) energy[row] = sqrtf(n2);
}

__global__ void mean_energy_kernel(const float* __restrict__ energy, float* __restrict__ thr){
  int b = blockIdx.x, t = threadIdx.x;
  float s = 0.f;
  for (int j = t; j < SS; j += 256) s += energy[b * SS + j];
  __shared__ float scratch[4];
  float tot = block_sum256(s, scratch);
  if (t == 0) thr[b] = tot * (1.0f / SS);
}

__global__ void tunnel_kernel(const float* __restrict__ ev, const float* __restrict__ energy,
                              const float* __restrict__ thr,
                              unsigned short* __restrict__ hi, unsigned short* __restrict__ lo){
  int row = blockIdx.x, t = threadIdx.x;
  float scale = (energy[row] < thr[row >> 11]) ? TUNNEL_SCALE : 1.0f;
  long base = (long)row * DD + t * 4;
  float4 v = *(const float4*)(ev + base);
  v.x *= scale; v.y *= scale; v.z *= scale; v.w *= scale;
  ushort4 hv, lv;
  hv.x = f2bf(v.x); lv.x = f2bf(v.x - bf2f(hv.x));
  hv.y = f2bf(v.y); lv.y = f2bf(v.y - bf2f(hv.y));
  hv.z = f2bf(v.z); lv.z = f2bf(v.z - bf2f(hv.z));
  hv.w = f2bf(v.w); lv.w = f2bf(v.w - bf2f(hv.w));
  *(ushort4*)(hi + base) = hv; *(ushort4*)(lo + base) = lv;
}

__global__ void ln_kernel(const float* __restrict__ h, const float* __restrict__ w,
                          const float* __restrict__ b, float* __restrict__ s_f32,
                          unsigned short* __restrict__ hi, unsigned short* __restrict__ lo){
  int row = blockIdx.x, t = threadIdx.x;
  long base = (long)row * DD + t * 4;
  float4 xv = *(const float4*)(h + base);
  __shared__ float scratch[4];
  float sum = block_sum256(xv.x + xv.y + xv.z + xv.w, scratch);
  float ssq = block_sum256(xv.x*xv.x + xv.y*xv.y + xv.z*xv.z + xv.w*xv.w, scratch);
  float mu = sum * (1.0f / DD);
  float var = ssq * (1.0f / DD) - mu * mu;
  float rstd = rsqrtf(var + 1e-5f);
  float4 wv = *(const float4*)(w + t * 4), bv = *(const float4*)(b + t * 4);
  float y0 = (xv.x - mu) * rstd * wv.x + bv.x;
  float y1 = (xv.y - mu) * rstd * wv.y + bv.y;
  float y2 = (xv.z - mu) * rstd * wv.z + bv.z;
  float y3 = (xv.w - mu) * rstd * wv.w + bv.w;
  float4 o; o.x = y0; o.y = y1; o.z = y2; o.w = y3;
  *(float4*)(s_f32 + base) = o;
  ushort4 hv, lv;
  hv.x = f2bf(y0); lv.x = f2bf(y0 - bf2f(hv.x));
  hv.y = f2bf(y1); lv.y = f2bf(y1 - bf2f(hv.y));
  hv.z = f2bf(y2); lv.z = f2bf(y2 - bf2f(hv.z));
  hv.w = f2bf(y3); lv.w = f2bf(y3 - bf2f(hv.w));
  *(ushort4*)(hi + base) = hv; *(ushort4*)(lo + base) = lv;
}

// final LN + unit-normalize -> bf16 (plain; un-amplified error)
__global__ void fln_kernel(const float* __restrict__ s, const float* __restrict__ w,
                           const float* __restrict__ b, unsigned short* __restrict__ uhi){
  int row = blockIdx.x, t = threadIdx.x;
  long base = (long)row * DD + t * 4;
  float4 xv = *(const float4*)(s + base);
  __shared__ float scratch[4];
  float sum = block_sum256(xv.x + xv.y + xv.z + xv.w, scratch);
  float ssq = block_sum256(xv.x*xv.x + xv.y*xv.y + xv.z*xv.z + xv.w*xv.w, scratch);
  float mu = sum * (1.0f / DD);
  float var = ssq * (1.0f / DD) - mu * mu;
  float rstd = rsqrtf(var + 1e-5f);
  float4 wv = *(const float4*)(w + t * 4), bv = *(const float4*)(b + t * 4);
  float y0 = (xv.x - mu) * rstd * wv.x + bv.x;
  float y1 = (xv.y - mu) * rstd * wv.y + bv.y;
  float y2 = (xv.z - mu) * rstd * wv.z + bv.z;
  float y3 = (xv.w - mu) * rstd * wv.w + bv.w;
  float n2 = block_sum256(y0*y0 + y1*y1 + y2*y2 + y3*y3, scratch);
  float inv = 1.0f / (sqrtf(n2) + 1e-12f);
  ushort4 o;
  o.x = f2bf(y0 * inv); o.y = f2bf(y1 * inv);
  o.z = f2bf(y2 * inv); o.w = f2bf(y3 * inv);
  *(ushort4*)(uhi + base) = o;
}

// ---------------- loss --------------------------------------------------------------
__global__ void loss_rows_kernel(const float* __restrict__ logits, const int* __restrict__ labels,
                                 float* __restrict__ lrow){
  int idx = blockIdx.x;               // 0..4093
  int b = idx / (SS - 1), q = idx - b * (SS - 1);
  const float* rowp = logits + (long)(b * SS + q) * VV;
  int t = threadIdx.x;
  float m = -1e30f, l = 0.f;
  for (int j = t; j < VV / 4; j += 256){
    float4 v = *(const float4*)(rowp + j * 4);
    float mv = fmaxf(fmaxf(v.x, v.y), fmaxf(v.z, v.w));
    if (mv > m){ l *= __expf(m - mv); m = mv; }
    l += __expf(v.x - m) + __expf(v.y - m) + __expf(v.z - m) + __expf(v.w - m);
  }
  __shared__ float sm[256], sl[256];
  sm[t] = m; sl[t] = l;
  __syncthreads();
  for (int off = 128; off; off >>= 1){
    if (t < off){
      float m2 = sm[t + off], l2 = sl[t + off];
      float M = fmaxf(sm[t], m2);
      sl[t] = sl[t] * __expf(sm[t] - M) + l2 * __expf(m2 - M);
      sm[t] = M;
    }
    __syncthreads();
  }
  if (t == 0){
    float lse = sm[0] + __logf(sl[0]);
    float tl = rowp[labels[b * SS + q + 1]];
    lrow[idx] = lse - tl;
  }
}

__global__ void loss_reduce_kernel(const float* __restrict__ lrow, float* __restrict__ dst){
  __shared__ float scratch[4];
  float s = 0.f;
  for (int j = threadIdx.x; j < BB * (SS - 1); j += 256) s += lrow[j];
  float tot = block_sum256(s, scratch);
  if (threadIdx.x == 0) dst[0] = tot / (float)(BB * (SS - 1));
}

// ---------------- launch ------------------------------------------------------------
extern "C" void kernel_launch(void* const* d_in, const int* in_sizes, int n_in,
                              void* d_out, int out_size, void* d_ws, size_t ws_size,
                              hipStream_t stream) {
  const int*   ids    = (const int*)d_in[0];
  const int*   labels = (const int*)d_in[1];
  const float* proj_w = (const float*)d_in[2];
  const float* proj_b = (const float*)d_in[3];
  const float* ln_w   = (const float*)d_in[4];
  const float* ln_b   = (const float*)d_in[5];
  const float* fln_w  = (const float*)d_in[6];
  const float* fln_b  = (const float*)d_in[7];
  const float* out_w  = (const float*)d_in[8];
  float* out = (float*)d_out;

  char* ws = (char*)d_ws;
  float*          s_f32 = (float*)(ws + 0);                    // 16.78 MB
  unsigned short* op_hi = (unsigned short*)(ws + 16777216);    //  8.39 MB (states/mid/ev/u hi)
  unsigned short* op_lo = (unsigned short*)(ws + 25165824);    //  8.39 MB
  unsigned short* T_hi  = (unsigned short*)(ws + 33554432);    //  8.39 MB (transposed operand)
  unsigned short* T_lo  = (unsigned short*)(ws + 41943040);    //  8.39 MB
  float*          k1    = (float*)(ws + 50331648);             // 16.78 MB (also h pre-LN)
  float*          k2    = (float*)(ws + 67108864);             // 16.78 MB (ev)
  unsigned short* sc_hi = (unsigned short*)(ws + 83886080);    //  8.39 MB (score hi)
  unsigned short* sc_lo = (unsigned short*)(ws + 92274688);    //  8.39 MB
  unsigned short* WhiT  = (unsigned short*)(ws + 100663296);   // 16.78 MB [L][n][k]
  unsigned short* WloT  = (unsigned short*)(ws + 117440512);   // 16.78 MB
  float*          energy= (float*)(ws + 134217728);
  float*          thr   = (float*)(ws + 134234112);
  float*          lrow  = (float*)(ws + 134234368);
  unsigned short* owT   = T_hi;  // 65.54 MB, overlays T/k/score zone (dead at vocab time)

  // proj_w [L][k][n] -> WhiT/WloT [L][n][k] (fp32-split bf16)
  transpose_f32_bf16_kernel<true><<<dim3(16, 16, 8), 256, 0, stream>>>(proj_w, WhiT, WloT, DD, DD);
  // encode
  encode_kernel<<<NROWS, 256, 0, stream>>>(ids, s_f32, op_hi, op_lo);
  transpose_bf16_pair_kernel<<<dim3(16, 32, 4), 256, 0, stream>>>(op_hi, op_lo, T_hi, T_lo, SS, DD);

  for (int l = 0; l < LL; ++l){
    // score1 = tril(states @ statesT)/32  -> bf16 hi/lo
    gemm_nt_kernel<2, 1><<<dim3(256, 2), 512, 0, stream>>>(
        op_hi, op_lo, op_hi, op_lo, nullptr, sc_hi, sc_lo, nullptr, nullptr, nullptr,
        DD, DD, DD, SS, 16, 16, (long)SS * DD, (long)SS * DD, (long)SS * SS, 0.03125f);
    // k1 = score1 @ states ; fused: mid = states + dt*k1 -> op hi/lo
    gemm_nt_kernel<3, 2><<<dim3(128, 2), 512, 0, stream>>>(
        sc_hi, sc_lo, T_hi, T_lo, k1, op_hi, op_lo, nullptr, s_f32, nullptr,
        SS, SS, SS, DD, 16, 8, (long)SS * SS, (long)DD * SS, (long)SS * DD, 1.0f);
    transpose_bf16_pair_kernel<<<dim3(16, 32, 4), 256, 0, stream>>>(op_hi, op_lo, T_hi, T_lo, SS, DD);
    // score2 = tril(mid @ midT)/32
    gemm_nt_kernel<2, 1><<<dim3(256, 2), 512, 0, stream>>>(
        op_hi, op_lo, op_hi, op_lo, nullptr, sc_hi, sc_lo, nullptr, nullptr, nullptr,
        DD, DD, DD, SS, 16, 16, (long)SS * DD, (long)SS * DD, (long)SS * SS, 0.03125f);
    // k2 = score2 @ mid ; fused: ev = states + 0.5dt*(k1+k2)  (written to k2 buffer)
    gemm_nt_kernel<4, 2><<<dim3(128, 2), 512, 0, stream>>>(
        sc_hi, sc_lo, T_hi, T_lo, k2, nullptr, nullptr, nullptr, s_f32, k1,
        SS, SS, SS, DD, 16, 8, (long)SS * SS, (long)DD * SS, (long)SS * DD, 1.0f);
    // row energies + threshold + tunneling
    energy_kernel<<<NROWS, 256, 0, stream>>>(k2, energy);
    mean_energy_kernel<<<BB, 256, 0, stream>>>(energy, thr);
    tunnel_kernel<<<NROWS, 256, 0, stream>>>(k2, energy, thr, op_hi, op_lo);
    // h = ev @ proj_w[l] + proj_b[l]  (into k1)
    gemm_nt_kernel<0, 0><<<dim3(256, 1), 512, 0, stream>>>(
        op_hi, op_lo, WhiT + (long)l * DD * DD, WloT + (long)l * DD * DD,
        k1, nullptr, nullptr, proj_b + l * DD, nullptr, nullptr,
        DD, DD, DD, DD, 32, 8, 0, 0, 0, 1.0f);
    // states = LN(h)
    ln_kernel<<<NROWS, 256, 0, stream>>>(k1, ln_w + l * DD, ln_b + l * DD, s_f32, op_hi, op_lo);
    if (l < LL - 1){
      transpose_bf16_pair_kernel<<<dim3(16, 32, 4), 256, 0, stream>>>(op_hi, op_lo, T_hi, T_lo, SS, DD);
    }
  }

  // out_w [k][v] -> owT [v][k] bf16 (plain); u = unit(LN(states)) -> op_hi
  transpose_f32_bf16_kernel<false><<<dim3(500, 16, 1), 256, 0, stream>>>(out_w, owT, nullptr, DD, VV);
  fln_kernel<<<NROWS, 256, 0, stream>>>(s_f32, fln_w, fln_b, op_hi);
  // logits = u @ out_w  (plain bf16, 256^2 multi-phase)
  gemm256_kernel<<<2000, 512, 0, stream>>>(op_hi, owT, out);
  // loss
  loss_rows_kernel<<<BB * (SS - 1), 256, 0, stream>>>(out, labels, lrow);
  loss_reduce_kernel<<<1, 256, 0, stream>>>(lrow, out + (long)NROWS * VV);
}